// Round 8
// baseline (111.477 us; speedup 1.0000x reference)
//
#include <hip/hip_runtime.h>
#include <math.h>

// Problem constants (from reference setup_inputs)
#define B 64
#define S 2048
#define H 1024
#define THREADS 256
#define WAVES 4

// ---------------------------------------------------------------------------
// Pass 1: fused score + online-softmax context accumulation.
// Loop body VERBATIM from the proven R1/R7 kernel. Only geometry (SPLIT) is
// templated: SPLIT=32 -> 2048 blocks -> ~5 blocks/CU resident (vs 4), +25%
// in-flight load streams. PLAIN __launch_bounds__(256): a min-waves cap
// spilled in R2/R4 (-25..-60 us); never constrain the allocator here.
// ---------------------------------------------------------------------------
template <int SPLIT>
__global__ __launch_bounds__(THREADS)
void luong_pass1(const float* __restrict__ dec_h,
                 const float* __restrict__ dec_c,
                 const float* __restrict__ enc,
                 float* __restrict__ attn_raw,   // d_out + B*H, raw scores
                 float* __restrict__ ctx_part,   // [B][SPLIT][H]
                 float* __restrict__ mz_part) {  // [B][SPLIT][2]
  constexpr int RPB = S / SPLIT;          // rows per block
  constexpr int RPW = RPB / WAVES;        // rows per wave

  const int bid  = blockIdx.x;
  const int b    = bid / SPLIT;
  const int sp   = bid % SPLIT;
  const int t    = threadIdx.x;
  const int w    = t >> 6;     // wave id 0..3
  const int lane = t & 63;

  // dec = dec_h + dec_c, distributed 16 elems per lane (same for all waves)
  float4 dec[4];
  const float4* dh = (const float4*)(dec_h + (size_t)b * H);
  const float4* dc = (const float4*)(dec_c + (size_t)b * H);
#pragma unroll
  for (int c = 0; c < 4; ++c) {
    float4 a  = dh[c * 64 + lane];
    float4 bb = dc[c * 64 + lane];
    dec[c] = make_float4(a.x + bb.x, a.y + bb.y, a.z + bb.z, a.w + bb.w);
  }

  float m = -INFINITY;
  float Z = 0.f;
  float ctx[16];
#pragma unroll
  for (int k = 0; k < 16; ++k) ctx[k] = 0.f;

  const int s_base = sp * RPB + w;
  for (int r = 0; r < RPW; ++r) {
    const int s = s_base + r * WAVES;
    const float4* erow = (const float4*)(enc + ((size_t)b * S + s) * H);
    float4 e[4];
#pragma unroll
    for (int c = 0; c < 4; ++c) e[c] = erow[c * 64 + lane];

    // score = <enc_row, dec>
    float partial = 0.f;
#pragma unroll
    for (int c = 0; c < 4; ++c)
      partial += e[c].x * dec[c].x + e[c].y * dec[c].y +
                 e[c].z * dec[c].z + e[c].w * dec[c].w;
#pragma unroll
    for (int off = 32; off >= 1; off >>= 1)
      partial += __shfl_xor(partial, off, 64);
    const float score = partial;  // all 64 lanes hold it

    if (lane == 0) attn_raw[b * S + s] = score;  // raw score; fixed up later

    // online softmax update (wave-uniform branch)
    if (score > m) {
      const float f = expf(m - score);
      Z *= f;
#pragma unroll
      for (int k = 0; k < 16; ++k) ctx[k] *= f;
      m = score;
    }
    const float p = expf(score - m);
    Z += p;
#pragma unroll
    for (int c = 0; c < 4; ++c) {
      ctx[c * 4 + 0] += p * e[c].x;
      ctx[c * 4 + 1] += p * e[c].y;
      ctx[c * 4 + 2] += p * e[c].z;
      ctx[c * 4 + 3] += p * e[c].w;
    }
  }

  // ---- combine the 4 waves of this block via LDS ----
  __shared__ float ctx_lds[WAVES][H];  // 16 KiB
  __shared__ float mzs[WAVES][2];
#pragma unroll
  for (int c = 0; c < 4; ++c) {
    float4 v = make_float4(ctx[c * 4 + 0], ctx[c * 4 + 1],
                           ctx[c * 4 + 2], ctx[c * 4 + 3]);
    ((float4*)&ctx_lds[w][c * 256])[lane] = v;
  }
  if (lane == 0) { mzs[w][0] = m; mzs[w][1] = Z; }
  __syncthreads();

  const float M = fmaxf(fmaxf(mzs[0][0], mzs[1][0]),
                        fmaxf(mzs[2][0], mzs[3][0]));
  float fac[WAVES];
  float Zb = 0.f;
#pragma unroll
  for (int i = 0; i < WAVES; ++i) {
    fac[i] = expf(mzs[i][0] - M);
    Zb += mzs[i][1] * fac[i];
  }

  float* outp = ctx_part + ((size_t)b * SPLIT + sp) * H;
#pragma unroll
  for (int q = 0; q < 4; ++q) {
    const int h = q * 256 + t;
    float v = 0.f;
#pragma unroll
    for (int i = 0; i < WAVES; ++i) v += ctx_lds[i][h] * fac[i];
    outp[h] = v;
  }
  if (t == 0) {
    mz_part[(b * SPLIT + sp) * 2 + 0] = M;
    mz_part[(b * SPLIT + sp) * 2 + 1] = Zb;
  }
}

// ---------------------------------------------------------------------------
// Fused tail (R7-proven): ONE kernel, grid = B*4 = 256 blocks. Block (b, q4):
// redundantly merges the SPLIT tiny (M,Z) partials (L2-hot), writes its
// quarter of context[b], normalizes its quarter of attn[b] in place.
// ---------------------------------------------------------------------------
template <int SPLIT>
__global__ __launch_bounds__(256)
void luong_tail(const float* __restrict__ ctx_part,
                const float* __restrict__ mz_part,
                float* __restrict__ ctx_out,   // d_out, [B][H]
                float* __restrict__ attn) {    // d_out + B*H, raw -> weights
  const int b  = blockIdx.x >> 2;
  const int q4 = blockIdx.x & 3;
  const int t  = threadIdx.x;

  const float* mz = mz_part + (size_t)b * SPLIT * 2;

  float M = -INFINITY;
#pragma unroll
  for (int i = 0; i < SPLIT; ++i) M = fmaxf(M, mz[2 * i]);
  float fac[SPLIT];
  float Z = 0.f;
#pragma unroll
  for (int i = 0; i < SPLIT; ++i) {
    fac[i] = expf(mz[2 * i] - M);
    Z += mz[2 * i + 1] * fac[i];
  }
  const float invZ = 1.f / Z;

  // context quarter: h = q4*256 + t (ctx_part is L2/L3-hot)
  {
    const int h = q4 * 256 + t;
    float v = 0.f;
#pragma unroll
    for (int i = 0; i < SPLIT; ++i)
      v += ctx_part[((size_t)b * SPLIT + i) * H + h] * fac[i];
    ctx_out[(size_t)b * H + h] = v * invZ;
  }

  // attn quarter: s in [q4*512, q4*512 + 512), in-place normalize
#pragma unroll
  for (int k = 0; k < 2; ++k) {
    const int s = q4 * 512 + k * 256 + t;
    const size_t idx = (size_t)b * S + s;
    attn[idx] = expf(attn[idx] - M) * invZ;
  }
}

template <int SPLIT>
static void launch_all(const float* dec_h, const float* dec_c, const float* enc,
                       float* ctx_out, float* attn, void* d_ws,
                       hipStream_t stream) {
  float* ctx_part = (float*)d_ws;                       // B*SPLIT*H floats
  float* mz_part  = ctx_part + (size_t)B * SPLIT * H;   // B*SPLIT*2
  luong_pass1<SPLIT><<<B * SPLIT, THREADS, 0, stream>>>(dec_h, dec_c, enc,
                                                        attn, ctx_part, mz_part);
  luong_tail<SPLIT><<<B * 4, 256, 0, stream>>>(ctx_part, mz_part, ctx_out, attn);
}

extern "C" void kernel_launch(void* const* d_in, const int* in_sizes, int n_in,
                              void* d_out, int out_size, void* d_ws, size_t ws_size,
                              hipStream_t stream) {
  const float* dec_h = (const float*)d_in[0];
  const float* dec_c = (const float*)d_in[1];
  const float* enc   = (const float*)d_in[2];

  float* ctx_out = (float*)d_out;            // [B][H]
  float* attn    = (float*)d_out + B * H;    // [B][S]

  const size_t need32 = ((size_t)B * 32 * H + (size_t)B * 32 * 2) * sizeof(float);
  if (ws_size >= need32) {
    launch_all<32>(dec_h, dec_c, enc, ctx_out, attn, d_ws, stream);
  } else {
    launch_all<16>(dec_h, dec_c, enc, ctx_out, attn, d_ws, stream);
  }
}

// Round 9
// 102.163 us; speedup vs baseline: 1.0912x; 1.0912x over previous
//
#include <hip/hip_runtime.h>
#include <math.h>

// Problem constants (from reference setup_inputs)
#define B 64
#define S 2048
#define H 1024
#define SPLIT 16
#define ROWS_PER_BLOCK (S / SPLIT)              // 128
#define THREADS 256
#define WAVES 4
#define ROWS_PER_WAVE (ROWS_PER_BLOCK / WAVES)  // 32

// ---------------------------------------------------------------------------
// R9 = exact revert to the R7 configuration (best: 102.4 us).
// Session ledger (axes tested, one variable at a time):
//   - prefetch depth 2/3-slot: NEUTRAL (R1=R3=114.6/116.1)
//   - __launch_bounds__ min-waves cap (VGPR cap 128/102): SPILLS, -25..-60 us
//     (R2: 175, R4: 141) — never constrain the allocator on this loop
//   - cooperative kernel + grid.sync: FAILS graph capture silently (R5)
//   - single kernel w/ atomic last-block tail: codegen collapse, VGPR 40,
//     remat-bound loop at 757 GB/s (R6: 320 us)
//   - fused 256-block tail kernel: WIN, -12 us (R7: 102.4)
//   - SPLIT=32 (2048 blocks): REGRESSED +9 us — 2 dispatch rounds at
//     4 blocks/CU (R8: 111.5)
// Standing decomposition: pass1 ~97 us = 512 MiB @ ~5.5 TB/s (87% of the
// 6.3 TB/s measured read ceiling); tail ~5 us. Structural floor = one full
// enc read. This is the roofline config.
// ---------------------------------------------------------------------------
__global__ __launch_bounds__(THREADS)
void luong_pass1(const float* __restrict__ dec_h,
                 const float* __restrict__ dec_c,
                 const float* __restrict__ enc,
                 float* __restrict__ attn_raw,   // d_out + B*H, raw scores
                 float* __restrict__ ctx_part,   // [B][SPLIT][H]
                 float* __restrict__ mz_part) {  // [B][SPLIT][2]
  const int bid  = blockIdx.x;
  const int b    = bid / SPLIT;
  const int sp   = bid % SPLIT;
  const int t    = threadIdx.x;
  const int w    = t >> 6;     // wave id 0..3
  const int lane = t & 63;

  // dec = dec_h + dec_c, distributed 16 elems per lane (same for all waves)
  float4 dec[4];
  const float4* dh = (const float4*)(dec_h + (size_t)b * H);
  const float4* dc = (const float4*)(dec_c + (size_t)b * H);
#pragma unroll
  for (int c = 0; c < 4; ++c) {
    float4 a  = dh[c * 64 + lane];
    float4 bb = dc[c * 64 + lane];
    dec[c] = make_float4(a.x + bb.x, a.y + bb.y, a.z + bb.z, a.w + bb.w);
  }

  float m = -INFINITY;
  float Z = 0.f;
  float ctx[16];
#pragma unroll
  for (int k = 0; k < 16; ++k) ctx[k] = 0.f;

  const int s_base = sp * ROWS_PER_BLOCK + w;
  for (int r = 0; r < ROWS_PER_WAVE; ++r) {
    const int s = s_base + r * WAVES;
    const float4* erow = (const float4*)(enc + ((size_t)b * S + s) * H);
    float4 e[4];
#pragma unroll
    for (int c = 0; c < 4; ++c) e[c] = erow[c * 64 + lane];

    // score = <enc_row, dec>
    float partial = 0.f;
#pragma unroll
    for (int c = 0; c < 4; ++c)
      partial += e[c].x * dec[c].x + e[c].y * dec[c].y +
                 e[c].z * dec[c].z + e[c].w * dec[c].w;
#pragma unroll
    for (int off = 32; off >= 1; off >>= 1)
      partial += __shfl_xor(partial, off, 64);
    const float score = partial;  // all 64 lanes hold it

    if (lane == 0) attn_raw[b * S + s] = score;  // raw score; fixed up later

    // online softmax update (wave-uniform branch)
    if (score > m) {
      const float f = expf(m - score);
      Z *= f;
#pragma unroll
      for (int k = 0; k < 16; ++k) ctx[k] *= f;
      m = score;
    }
    const float p = expf(score - m);
    Z += p;
#pragma unroll
    for (int c = 0; c < 4; ++c) {
      ctx[c * 4 + 0] += p * e[c].x;
      ctx[c * 4 + 1] += p * e[c].y;
      ctx[c * 4 + 2] += p * e[c].z;
      ctx[c * 4 + 3] += p * e[c].w;
    }
  }

  // ---- combine the 4 waves of this block via LDS ----
  __shared__ float ctx_lds[WAVES][H];  // 16 KiB
  __shared__ float mzs[WAVES][2];
#pragma unroll
  for (int c = 0; c < 4; ++c) {
    float4 v = make_float4(ctx[c * 4 + 0], ctx[c * 4 + 1],
                           ctx[c * 4 + 2], ctx[c * 4 + 3]);
    ((float4*)&ctx_lds[w][c * 256])[lane] = v;
  }
  if (lane == 0) { mzs[w][0] = m; mzs[w][1] = Z; }
  __syncthreads();

  const float M = fmaxf(fmaxf(mzs[0][0], mzs[1][0]),
                        fmaxf(mzs[2][0], mzs[3][0]));
  float fac[WAVES];
  float Zb = 0.f;
#pragma unroll
  for (int i = 0; i < WAVES; ++i) {
    fac[i] = expf(mzs[i][0] - M);
    Zb += mzs[i][1] * fac[i];
  }

  float* outp = ctx_part + ((size_t)b * SPLIT + sp) * H;
#pragma unroll
  for (int q = 0; q < 4; ++q) {
    const int h = q * 256 + t;
    float v = 0.f;
#pragma unroll
    for (int i = 0; i < WAVES; ++i) v += ctx_lds[i][h] * fac[i];
    outp[h] = v;
  }
  if (t == 0) {
    mz_part[(b * SPLIT + sp) * 2 + 0] = M;
    mz_part[(b * SPLIT + sp) * 2 + 1] = Zb;
  }
}

// ---------------------------------------------------------------------------
// Fused tail (R7-proven): ONE kernel, grid = B*4 = 256 blocks. Block (b, q4):
// redundantly merges the 16 tiny (M,Z) partials (L2-hot), writes its quarter
// of context[b], normalizes its quarter of attn[b] in place.
// ---------------------------------------------------------------------------
__global__ __launch_bounds__(256)
void luong_tail(const float* __restrict__ ctx_part,
                const float* __restrict__ mz_part,
                float* __restrict__ ctx_out,   // d_out, [B][H]
                float* __restrict__ attn) {    // d_out + B*H, raw -> weights
  const int b  = blockIdx.x >> 2;
  const int q4 = blockIdx.x & 3;
  const int t  = threadIdx.x;

  const float* mz = mz_part + (size_t)b * SPLIT * 2;

  float M = -INFINITY;
#pragma unroll
  for (int i = 0; i < SPLIT; ++i) M = fmaxf(M, mz[2 * i]);
  float fac[SPLIT];
  float Z = 0.f;
#pragma unroll
  for (int i = 0; i < SPLIT; ++i) {
    fac[i] = expf(mz[2 * i] - M);
    Z += mz[2 * i + 1] * fac[i];
  }
  const float invZ = 1.f / Z;

  // context quarter: h = q4*256 + t (ctx_part is L2/L3-hot)
  {
    const int h = q4 * 256 + t;
    float v = 0.f;
#pragma unroll
    for (int i = 0; i < SPLIT; ++i)
      v += ctx_part[((size_t)b * SPLIT + i) * H + h] * fac[i];
    ctx_out[(size_t)b * H + h] = v * invZ;
  }

  // attn quarter: s in [q4*512, q4*512 + 512), in-place normalize
#pragma unroll
  for (int k = 0; k < 2; ++k) {
    const int s = q4 * 512 + k * 256 + t;
    const size_t idx = (size_t)b * S + s;
    attn[idx] = expf(attn[idx] - M) * invZ;
  }
}

extern "C" void kernel_launch(void* const* d_in, const int* in_sizes, int n_in,
                              void* d_out, int out_size, void* d_ws, size_t ws_size,
                              hipStream_t stream) {
  const float* dec_h = (const float*)d_in[0];
  const float* dec_c = (const float*)d_in[1];
  const float* enc   = (const float*)d_in[2];

  float* ctx_out = (float*)d_out;            // [B][H]
  float* attn    = (float*)d_out + B * H;    // [B][S]

  float* ctx_part = (float*)d_ws;                       // B*SPLIT*H floats = 4 MiB
  float* mz_part  = ctx_part + (size_t)B * SPLIT * H;   // B*SPLIT*2

  luong_pass1<<<B * SPLIT, THREADS, 0, stream>>>(dec_h, dec_c, enc, attn,
                                                 ctx_part, mz_part);
  luong_tail<<<B * 4, 256, 0, stream>>>(ctx_part, mz_part, ctx_out, attn);
}